// Round 2
// baseline (679.547 us; speedup 1.0000x reference)
//
#include <hip/hip_runtime.h>

typedef __bf16 bf16x8 __attribute__((ext_vector_type(8)));
typedef unsigned short u16x8 __attribute__((ext_vector_type(8)));
typedef float f32x4 __attribute__((ext_vector_type(4)));

#define MFMA(a, b, c) __builtin_amdgcn_mfma_f32_16x16x32_bf16(a, b, c, 0, 0, 0)

constexpr int L = 1024;
constexpr int D = 64;
constexpr int QT = 16;                        // q rows per workgroup
constexpr int BH = 128;                       // B*H
constexpr size_t OUT_ELEMS = 8ull * 16 * 1024 * 64;
constexpr size_t PLANE = (size_t)BH * L * D;  // 8,388,608 elems per plane

__device__ __forceinline__ unsigned short f2bf(float x) {
    unsigned int u = __float_as_uint(x);
    u = u + 0x7FFFu + ((u >> 16) & 1u);       // round-to-nearest-even
    return (unsigned short)(u >> 16);
}
__device__ __forceinline__ float bf2f(unsigned short h) {
    return __uint_as_float(((unsigned int)h) << 16);
}
// element-space XOR swizzle: permutes 16B blocks within a row (bits 2-4 of col)
__device__ __forceinline__ int swz(int row, int col) {
    return row * L + (col ^ ((row & 7) << 2));
}

__device__ __forceinline__ void load_split8(const float* src, bf16x8& hi, bf16x8& lo) {
    float4 a0 = *(const float4*)(src);
    float4 a1 = *(const float4*)(src + 4);
    float xs[8] = {a0.x, a0.y, a0.z, a0.w, a1.x, a1.y, a1.z, a1.w};
    u16x8 hb, lb;
#pragma unroll
    for (int j = 0; j < 8; ++j) {
        unsigned short h = f2bf(xs[j]);
        hb[j] = h;
        lb[j] = f2bf(xs[j] - bf2f(h));
    }
    hi = __builtin_bit_cast(bf16x8, hb);
    lo = __builtin_bit_cast(bf16x8, lb);
}

// ---------------- prep kernel 1: K -> Khi/Klo planes (same layout) ----------------
__global__ __launch_bounds__(256)
void conv_k(const float* __restrict__ kg, unsigned short* __restrict__ khi,
            unsigned short* __restrict__ klo) {
    const size_t t = (size_t)blockIdx.x * 256 + threadIdx.x;   // one 8-elem item
    const float* src = kg + t * 8;
    float4 a0 = *(const float4*)(src);
    float4 a1 = *(const float4*)(src + 4);
    float xs[8] = {a0.x, a0.y, a0.z, a0.w, a1.x, a1.y, a1.z, a1.w};
    u16x8 hb, lb;
#pragma unroll
    for (int j = 0; j < 8; ++j) {
        unsigned short h = f2bf(xs[j]);
        hb[j] = h;
        lb[j] = f2bf(xs[j] - bf2f(h));
    }
    *(u16x8*)(khi + t * 8) = hb;
    *(u16x8*)(klo + t * 8) = lb;
}

// ------- prep kernel 2: V [bh][k][d] -> Vthi/Vtlo [bh][d][k] (transpose) -------
__global__ __launch_bounds__(256)
void conv_v(const float* __restrict__ vg, unsigned short* __restrict__ vthi,
            unsigned short* __restrict__ vtlo) {
    __shared__ __align__(16) unsigned short hi[64][72];
    __shared__ __align__(16) unsigned short lo[64][72];
    const int bh = blockIdx.x >> 4;
    const int k0 = (blockIdx.x & 15) * 64;
    const int tid = threadIdx.x;
    // read 64k x 64d tile, coalesced; scatter-transposed into LDS
#pragma unroll
    for (int r = 0; r < 4; ++r) {
        const int k  = r * 16 + (tid >> 4);
        const int d0 = (tid & 15) * 4;
        float4 a = *(const float4*)(vg + ((size_t)(bh * L + k0 + k)) * D + d0);
        float xs[4] = {a.x, a.y, a.z, a.w};
#pragma unroll
        for (int j = 0; j < 4; ++j) {
            unsigned short h = f2bf(xs[j]);
            hi[d0 + j][k] = h;
            lo[d0 + j][k] = f2bf(xs[j] - bf2f(h));
        }
    }
    __syncthreads();
    // write out rows of Vt, coalesced-ish (8B per lane)
#pragma unroll
    for (int w = 0; w < 4; ++w) {
        const int d   = w * 16 + (tid >> 4);
        const int kk0 = (tid & 15) * 4;
        const size_t dst = (size_t)bh * (D * L) + (size_t)d * L + k0 + kk0;
        *(unsigned long long*)(vthi + dst) = *(const unsigned long long*)&hi[d][kk0];
        *(unsigned long long*)(vtlo + dst) = *(const unsigned long long*)&lo[d][kk0];
    }
}

// ---------------- main fused kernel (pre-converted K/Vt in ws) ----------------
__global__ __launch_bounds__(256, 2)
void attn_main(const float* __restrict__ qg, const unsigned short* __restrict__ khi_g,
               const unsigned short* __restrict__ klo_g,
               const unsigned short* __restrict__ vthi_g,
               const unsigned short* __restrict__ vtlo_g,
               const float* __restrict__ biasg, const int* __restrict__ maskg,
               float* __restrict__ outg) {
    __shared__ unsigned int lds[QT * L];      // 64 KiB: S (f32) then P packed {hi,lo}

    // bijective XCD swizzle: 8192 % 8 == 0
    const int wg = (blockIdx.x & 7) * 1024 + (blockIdx.x >> 3);
    const int bh = wg >> 6;
    const int qt = wg & 63;
    const int b  = bh >> 4;
    const int q0 = qt * QT;
    const int tid  = threadIdx.x;
    const int wave = tid >> 6;
    const int lane = tid & 63;
    const int lg   = lane >> 4;
    const int lr   = lane & 15;

    const float* qp = qg + (size_t)bh * L * D;
    const unsigned short* khi = khi_g + (size_t)bh * L * D;
    const unsigned short* klo = klo_g + (size_t)bh * L * D;
    const unsigned short* vthi = vthi_g + (size_t)bh * D * L;
    const unsigned short* vtlo = vtlo_g + (size_t)bh * D * L;

    // Q fragments (hi/lo split); A-frag: row = lane&15, k = (lane>>4)*8 + j
    bf16x8 qhi[2], qlo[2];
#pragma unroll
    for (int s = 0; s < 2; ++s) {
        load_split8(qp + (size_t)(q0 + lr) * D + s * 32 + lg * 8, qhi[s], qlo[s]);
    }

    // ---- QK^T -> LDS (raw dot products, fp32) ----
    const int cbase = wave * 256;
#pragma unroll 2
    for (int ct = 0; ct < 16; ++ct) {
        const int cb = cbase + ct * 16;
        const unsigned short* krow = khi + (size_t)(cb + lr) * D + lg * 8;
        const unsigned short* lrow = klo + (size_t)(cb + lr) * D + lg * 8;
        f32x4 acc = {0.f, 0.f, 0.f, 0.f};
#pragma unroll
        for (int s = 0; s < 2; ++s) {
            bf16x8 kh = __builtin_bit_cast(bf16x8, *(const u16x8*)(krow + s * 32));
            bf16x8 kl = __builtin_bit_cast(bf16x8, *(const u16x8*)(lrow + s * 32));
            acc = MFMA(qhi[s], kh, acc);
            acc = MFMA(qlo[s], kh, acc);
            acc = MFMA(qhi[s], kl, acc);
        }
#pragma unroll
        for (int r = 0; r < 4; ++r) {
            lds[swz(lg * 4 + r, cb + lr)] = __float_as_uint(acc[r]);
        }
    }
    __syncthreads();

    // ---- softmax: wave w owns rows 4w..4w+3 ----
    const float* bbase = biasg + (size_t)b * L * L;
    const int*   mbase = maskg + (size_t)b * L * L;
    float* score = outg + OUT_ELEMS + (size_t)bh * L * L;
#pragma unroll
    for (int rr = 0; rr < 4; ++rr) {
        const int row  = wave * 4 + rr;
        const int grow = q0 + row;
        const float* brow = bbase + (size_t)grow * L;
        const int*   mrow = mbase + (size_t)grow * L;
        float sv[16];
        float mx = -3.0e38f;
#pragma unroll
        for (int i = 0; i < 16; ++i) {
            const int c = lane + 64 * i;
            float s = __uint_as_float(lds[swz(row, c)]);
            s = s * 0.125f * brow[c];
            if (mrow[c] == 0) s = -10000.0f;
            sv[i] = s;
            mx = fmaxf(mx, s);
        }
#pragma unroll
        for (int off = 32; off; off >>= 1) mx = fmaxf(mx, __shfl_xor(mx, off));
        float sum = 0.f;
#pragma unroll
        for (int i = 0; i < 16; ++i) { sv[i] = __expf(sv[i] - mx); sum += sv[i]; }
#pragma unroll
        for (int off = 32; off; off >>= 1) sum += __shfl_xor(sum, off);
        const float rinv = 1.0f / sum;
        float* srow = score + (size_t)grow * L;
#pragma unroll
        for (int i = 0; i < 16; ++i) {
            const int c = lane + 64 * i;
            const float p = sv[i] * rinv;
            srow[c] = p;                                    // coalesced 256B/instr
            unsigned short ph = f2bf(p);
            unsigned short pl = f2bf(p - bf2f(ph));
            lds[swz(row, c)] = ((unsigned int)pl << 16) | ph;   // in-place, same slot
        }
    }
    __syncthreads();

    // ---- PV: wave w owns d columns [16w,16w+16) ----
    const int d0 = wave * 16;
    const unsigned short* vhrow = vthi + (size_t)(d0 + lr) * L;
    const unsigned short* vlrow = vtlo + (size_t)(d0 + lr) * L;
    f32x4 oacc = {0.f, 0.f, 0.f, 0.f};
#pragma unroll 2
    for (int kb = 0; kb < L; kb += 32) {
        const int e0 = kb + lg * 8;
        uint4 ua = *(const uint4*)&lds[swz(lr, e0)];
        uint4 ub = *(const uint4*)&lds[swz(lr, e0 + 4)];
        unsigned int uu[8] = {ua.x, ua.y, ua.z, ua.w, ub.x, ub.y, ub.z, ub.w};
        u16x8 hb, lb;
#pragma unroll
        for (int j = 0; j < 8; ++j) {
            hb[j] = (unsigned short)(uu[j] & 0xFFFFu);
            lb[j] = (unsigned short)(uu[j] >> 16);
        }
        bf16x8 phi = __builtin_bit_cast(bf16x8, hb);
        bf16x8 plo = __builtin_bit_cast(bf16x8, lb);
        bf16x8 vhi = __builtin_bit_cast(bf16x8, *(const u16x8*)(vhrow + e0));
        bf16x8 vlo = __builtin_bit_cast(bf16x8, *(const u16x8*)(vlrow + e0));
        oacc = MFMA(phi, vhi, oacc);
        oacc = MFMA(plo, vhi, oacc);
        oacc = MFMA(phi, vlo, oacc);
    }
#pragma unroll
    for (int r = 0; r < 4; ++r) {
        outg[((size_t)bh * L + q0 + lg * 4 + r) * D + d0 + lr] = oacc[r];
    }
}

// ---------------- fallback (round-1 kernel, used only if ws too small) ----------------
__global__ __launch_bounds__(256, 2)
void attn_fused(const float* __restrict__ qg, const float* __restrict__ kg,
                const float* __restrict__ vg, const float* __restrict__ biasg,
                const int* __restrict__ maskg, float* __restrict__ outg) {
    __shared__ unsigned int lds[QT * L];

    const int wg = blockIdx.x;
    const int bh = wg >> 6;
    const int qt = wg & 63;
    const int b  = bh >> 4;
    const int q0 = qt * QT;
    const int tid  = threadIdx.x;
    const int wave = tid >> 6;
    const int lane = tid & 63;
    const int lg   = lane >> 4;
    const int lr   = lane & 15;

    const float* qp = qg + (size_t)bh * L * D;
    const float* kp = kg + (size_t)bh * L * D;
    const float* vp = vg + (size_t)bh * L * D;

    bf16x8 qhi[2], qlo[2];
#pragma unroll
    for (int s = 0; s < 2; ++s) {
        load_split8(qp + (size_t)(q0 + lr) * D + s * 32 + lg * 8, qhi[s], qlo[s]);
    }

    const int cbase = wave * 256;
#pragma unroll 2
    for (int ct = 0; ct < 16; ++ct) {
        const int cb = cbase + ct * 16;
        f32x4 acc = {0.f, 0.f, 0.f, 0.f};
#pragma unroll
        for (int s = 0; s < 2; ++s) {
            bf16x8 khi, klo;
            load_split8(kp + (size_t)(cb + lr) * D + s * 32 + lg * 8, khi, klo);
            acc = MFMA(qhi[s], khi, acc);
            acc = MFMA(qlo[s], khi, acc);
            acc = MFMA(qhi[s], klo, acc);
        }
#pragma unroll
        for (int r = 0; r < 4; ++r) {
            lds[swz(lg * 4 + r, cb + lr)] = __float_as_uint(acc[r]);
        }
    }
    __syncthreads();

    const float* bbase = biasg + (size_t)b * L * L;
    const int*   mbase = maskg + (size_t)b * L * L;
    float* score = outg + OUT_ELEMS + (size_t)bh * L * L;
#pragma unroll
    for (int rr = 0; rr < 4; ++rr) {
        const int row  = wave * 4 + rr;
        const int grow = q0 + row;
        const float* brow = bbase + (size_t)grow * L;
        const int*   mrow = mbase + (size_t)grow * L;
        float sv[16];
        float mx = -3.0e38f;
#pragma unroll
        for (int i = 0; i < 16; ++i) {
            const int c = lane + 64 * i;
            float s = __uint_as_float(lds[swz(row, c)]);
            s = s * 0.125f * brow[c];
            if (mrow[c] == 0) s = -10000.0f;
            sv[i] = s;
            mx = fmaxf(mx, s);
        }
#pragma unroll
        for (int off = 32; off; off >>= 1) mx = fmaxf(mx, __shfl_xor(mx, off));
        float sum = 0.f;
#pragma unroll
        for (int i = 0; i < 16; ++i) { sv[i] = __expf(sv[i] - mx); sum += sv[i]; }
#pragma unroll
        for (int off = 32; off; off >>= 1) sum += __shfl_xor(sum, off);
        const float rinv = 1.0f / sum;
        float* srow = score + (size_t)grow * L;
#pragma unroll
        for (int i = 0; i < 16; ++i) {
            const int c = lane + 64 * i;
            const float p = sv[i] * rinv;
            srow[c] = p;
            unsigned short ph = f2bf(p);
            unsigned short pl = f2bf(p - bf2f(ph));
            lds[swz(row, c)] = ((unsigned int)pl << 16) | ph;
        }
    }
    __syncthreads();

    const int d0 = wave * 16;
    f32x4 oacc = {0.f, 0.f, 0.f, 0.f};
#pragma unroll 2
    for (int kb = 0; kb < L; kb += 32) {
        const int e0 = kb + lg * 8;
        uint4 ua = *(const uint4*)&lds[swz(lr, e0)];
        uint4 ub = *(const uint4*)&lds[swz(lr, e0 + 4)];
        unsigned int uu[8] = {ua.x, ua.y, ua.z, ua.w, ub.x, ub.y, ub.z, ub.w};
        u16x8 hb, lb;
#pragma unroll
        for (int j = 0; j < 8; ++j) {
            hb[j] = (unsigned short)(uu[j] & 0xFFFFu);
            lb[j] = (unsigned short)(uu[j] >> 16);
        }
        bf16x8 phi = __builtin_bit_cast(bf16x8, hb);
        bf16x8 plo = __builtin_bit_cast(bf16x8, lb);
        u16x8 vh, vl;
#pragma unroll
        for (int j = 0; j < 8; ++j) {
            float x = vp[(size_t)(e0 + j) * D + d0 + lr];
            unsigned short h = f2bf(x);
            vh[j] = h;
            vl[j] = f2bf(x - bf2f(h));
        }
        bf16x8 vhi = __builtin_bit_cast(bf16x8, vh);
        bf16x8 vlo = __builtin_bit_cast(bf16x8, vl);
        oacc = MFMA(phi, vhi, oacc);
        oacc = MFMA(plo, vhi, oacc);
        oacc = MFMA(phi, vlo, oacc);
    }
#pragma unroll
    for (int r = 0; r < 4; ++r) {
        outg[((size_t)bh * L + q0 + lg * 4 + r) * D + d0 + lr] = oacc[r];
    }
}

extern "C" void kernel_launch(void* const* d_in, const int* in_sizes, int n_in,
                              void* d_out, int out_size, void* d_ws, size_t ws_size,
                              hipStream_t stream) {
    const float* q    = (const float*)d_in[0];
    const float* k    = (const float*)d_in[1];
    const float* v    = (const float*)d_in[2];
    const float* bias = (const float*)d_in[3];
    const int*   mask = (const int*)d_in[4];
    float* out = (float*)d_out;

    const size_t need = 4 * PLANE * sizeof(unsigned short);   // 64 MiB
    if (ws_size >= need) {
        unsigned short* khi  = (unsigned short*)d_ws;
        unsigned short* klo  = khi + PLANE;
        unsigned short* vthi = khi + 2 * PLANE;
        unsigned short* vtlo = khi + 3 * PLANE;
        hipLaunchKernelGGL(conv_k, dim3(PLANE / 8 / 256), dim3(256), 0, stream, k, khi, klo);
        hipLaunchKernelGGL(conv_v, dim3(BH * 16), dim3(256), 0, stream, v, vthi, vtlo);
        hipLaunchKernelGGL(attn_main, dim3(BH * (L / QT)), dim3(256), 0, stream,
                           q, khi, klo, vthi, vtlo, bias, mask, out);
    } else {
        hipLaunchKernelGGL(attn_fused, dim3(BH * (L / QT)), dim3(256), 0, stream,
                           q, k, v, bias, mask, out);
    }
}

// Round 3
// 380.329 us; speedup vs baseline: 1.7867x; 1.7867x over previous
//
#include <hip/hip_runtime.h>

typedef _Float16 f16x8 __attribute__((ext_vector_type(8)));
typedef _Float16 f16x4 __attribute__((ext_vector_type(4)));
typedef float f32x4 __attribute__((ext_vector_type(4)));

#define MFMA16(a, b, c) __builtin_amdgcn_mfma_f32_16x16x32_f16(a, b, c, 0, 0, 0)

constexpr int L = 1024;
constexpr int D = 64;
constexpr int QT = 16;                        // q rows per workgroup
constexpr int BH = 128;                       // B*H
constexpr size_t OUT_ELEMS = 8ull * 16 * 1024 * 64;
constexpr size_t PLANE = (size_t)BH * L * D;  // 8,388,608 elems
constexpr size_t BMN   = 8ull * 1024 * 1024;  // B*L*L bias/mask elems

// fp16-element LDS swizzle: XOR col bits [3:5] (16B blocks) with row&7
__device__ __forceinline__ int swzh(int row, int col) {
    return row * L + (col ^ ((row & 7) << 3));
}

// ---------------- prep 1: K -> fp16 plane, 0.125 scale folded in ----------------
__global__ __launch_bounds__(256)
void conv_k(const float* __restrict__ kg, _Float16* __restrict__ kf) {
    const size_t t = ((size_t)blockIdx.x * 256 + threadIdx.x) * 8;
    float4 a0 = *(const float4*)(kg + t);
    float4 a1 = *(const float4*)(kg + t + 4);
    f16x8 o;
    o[0] = (_Float16)(0.125f * a0.x); o[1] = (_Float16)(0.125f * a0.y);
    o[2] = (_Float16)(0.125f * a0.z); o[3] = (_Float16)(0.125f * a0.w);
    o[4] = (_Float16)(0.125f * a1.x); o[5] = (_Float16)(0.125f * a1.y);
    o[6] = (_Float16)(0.125f * a1.z); o[7] = (_Float16)(0.125f * a1.w);
    *(f16x8*)(kf + t) = o;
}

// ------- prep 2: V [bh][k][d] -> fp16 Vt [bh][d][k] (transpose via LDS) -------
__global__ __launch_bounds__(256)
void conv_v(const float* __restrict__ vg, _Float16* __restrict__ vtf) {
    __shared__ _Float16 tile[64][72];         // +8 pad breaks bank alias
    const int bh = blockIdx.x >> 4;
    const int k0 = (blockIdx.x & 15) * 64;
    const int tid = threadIdx.x;
#pragma unroll
    for (int r = 0; r < 4; ++r) {
        const int k  = r * 16 + (tid >> 4);
        const int d0 = (tid & 15) * 4;
        float4 a = *(const float4*)(vg + ((size_t)(bh * L + k0 + k)) * D + d0);
        tile[d0 + 0][k] = (_Float16)a.x;
        tile[d0 + 1][k] = (_Float16)a.y;
        tile[d0 + 2][k] = (_Float16)a.z;
        tile[d0 + 3][k] = (_Float16)a.w;
    }
    __syncthreads();
#pragma unroll
    for (int w = 0; w < 4; ++w) {
        const int d   = w * 16 + (tid >> 4);
        const int kk0 = (tid & 15) * 4;
        const size_t dst = (size_t)bh * (D * L) + (size_t)d * L + k0 + kk0;
        *(f16x4*)(vtf + dst) = *(const f16x4*)&tile[d][kk0];
    }
}

// ---------------- prep 3: fuse bias+mask: bm = mask ? bias : -1 ----------------
__global__ __launch_bounds__(256)
void conv_bm(const float* __restrict__ bias, const int* __restrict__ mask,
             float* __restrict__ bm) {
    const size_t t = ((size_t)blockIdx.x * 256 + threadIdx.x) * 4;
    float4 bv = *(const float4*)(bias + t);
    int4   mv = *(const int4*)(mask + t);
    float4 o;
    o.x = mv.x ? bv.x : -1.0f;
    o.y = mv.y ? bv.y : -1.0f;
    o.z = mv.z ? bv.z : -1.0f;
    o.w = mv.w ? bv.w : -1.0f;
    *(float4*)(bm + t) = o;
}

// ---------------- main fused kernel ----------------
__global__ __launch_bounds__(256, 5)
void attn_main(const float* __restrict__ qg, const _Float16* __restrict__ kf_g,
               const _Float16* __restrict__ vtf_g, const float* __restrict__ bmg,
               float* __restrict__ outg) {
    __shared__ _Float16 lds[QT * L];          // 32 KiB: S (fp16) then P in-place

    // bijective XCD swizzle: 8192 % 8 == 0
    const int wg = (blockIdx.x & 7) * 1024 + (blockIdx.x >> 3);
    const int bh = wg >> 6;
    const int qt = wg & 63;
    const int b  = bh >> 4;
    const int q0 = qt * QT;
    const int tid  = threadIdx.x;
    const int wave = tid >> 6;
    const int lane = tid & 63;
    const int lg   = lane >> 4;
    const int lr   = lane & 15;

    const float*    qp = qg + (size_t)bh * L * D;
    const _Float16* kp = kf_g + (size_t)bh * L * D;

    // Q fragments fp16; A-frag: row(q) = lane&15, k(d) = (lane>>4)*8 + j
    f16x8 qf[2];
#pragma unroll
    for (int s = 0; s < 2; ++s) {
        const float* qsrc = qp + (size_t)(q0 + lr) * D + s * 32 + lg * 8;
        float4 a0 = *(const float4*)qsrc;
        float4 a1 = *(const float4*)(qsrc + 4);
        f16x8 qv;
        qv[0] = (_Float16)a0.x; qv[1] = (_Float16)a0.y;
        qv[2] = (_Float16)a0.z; qv[3] = (_Float16)a0.w;
        qv[4] = (_Float16)a1.x; qv[5] = (_Float16)a1.y;
        qv[6] = (_Float16)a1.z; qv[7] = (_Float16)a1.w;
        qf[s] = qv;
    }

    // ---- QK^T -> LDS (raw 0.125*q.k, fp16) ----
    const int cbase = wave * 256;
#pragma unroll 4
    for (int ct = 0; ct < 16; ++ct) {
        const int cb = cbase + ct * 16;
        const _Float16* krow = kp + (size_t)(cb + lr) * D + lg * 8;
        f32x4 acc = {0.f, 0.f, 0.f, 0.f};
#pragma unroll
        for (int s = 0; s < 2; ++s) {
            f16x8 kv = *(const f16x8*)(krow + s * 32);
            acc = MFMA16(qf[s], kv, acc);
        }
        // D-frag: col(key) = lane&15, row(q) = (lane>>4)*4 + r
#pragma unroll
        for (int r = 0; r < 4; ++r) {
            lds[swzh(lg * 4 + r, cb + lr)] = (_Float16)acc[r];
        }
    }
    __syncthreads();

    // ---- softmax: wave w owns rows 4w..4w+3; bm = {bias | -1 if masked} ----
    const float* bmb = bmg + (size_t)b * L * L;
    float* score = outg + OUT_ELEMS + (size_t)bh * L * L;
#pragma unroll
    for (int rr = 0; rr < 4; ++rr) {
        const int row  = wave * 4 + rr;
        const int grow = q0 + row;
        const float* bmrow = bmb + (size_t)grow * L;
        float sv[16];
        float mx = -3.0e38f;
#pragma unroll
        for (int i = 0; i < 16; ++i) {
            const int c = lane + 64 * i;
            float s = (float)lds[swzh(row, c)];
            float t = bmrow[c];
            s = (t >= 0.f) ? s * t : -10000.0f;
            sv[i] = s;
            mx = fmaxf(mx, s);
        }
#pragma unroll
        for (int off = 32; off; off >>= 1) mx = fmaxf(mx, __shfl_xor(mx, off));
        float sum = 0.f;
#pragma unroll
        for (int i = 0; i < 16; ++i) { sv[i] = __expf(sv[i] - mx); sum += sv[i]; }
#pragma unroll
        for (int off = 32; off; off >>= 1) sum += __shfl_xor(sum, off);
        const float rinv = 1.0f / sum;
        float* srow = score + (size_t)grow * L;
#pragma unroll
        for (int i = 0; i < 16; ++i) {
            const int c = lane + 64 * i;
            const float p = sv[i] * rinv;
            srow[c] = p;                               // coalesced 256B/instr
            lds[swzh(row, c)] = (_Float16)p;           // in-place, same rows only
        }
    }
    __syncthreads();

    // ---- PV: wave w owns d columns [16w,16w+16) ----
    const int d0 = wave * 16;
    const _Float16* vrow = vtf_g + (size_t)bh * D * L + (size_t)(d0 + lr) * L;
    f32x4 oacc = {0.f, 0.f, 0.f, 0.f};
#pragma unroll 4
    for (int kb = 0; kb < L; kb += 32) {
        const int e0 = kb + lg * 8;
        // A-frag of P: row(q) = lane&15, k(key) = e0..e0+7 (16B, swizzle-aligned)
        f16x8 pa = *(const f16x8*)&lds[swzh(lr, e0)];
        // B-frag of V: col(d) = lane&15, k(key) = e0..e0+7
        f16x8 vb = *(const f16x8*)(vrow + e0);
        oacc = MFMA16(pa, vb, oacc);
    }
#pragma unroll
    for (int r = 0; r < 4; ++r) {
        outg[((size_t)bh * L + q0 + lg * 4 + r) * D + d0 + lr] = oacc[r];
    }
}

extern "C" void kernel_launch(void* const* d_in, const int* in_sizes, int n_in,
                              void* d_out, int out_size, void* d_ws, size_t ws_size,
                              hipStream_t stream) {
    const float* q    = (const float*)d_in[0];
    const float* k    = (const float*)d_in[1];
    const float* v    = (const float*)d_in[2];
    const float* bias = (const float*)d_in[3];
    const int*   mask = (const int*)d_in[4];
    float* out = (float*)d_out;

    const size_t need = 2 * PLANE * sizeof(_Float16) + BMN * sizeof(float);  // 64 MiB
    if (ws_size < need) return;               // empirically ws_size >= 64 MiB (R2)

    _Float16* kf  = (_Float16*)d_ws;          // [BH][L][D] fp16 (pre-scaled 0.125)
    _Float16* vtf = kf + PLANE;               // [BH][D][L] fp16
    float*    bm  = (float*)(vtf + PLANE);    // [B][L][L]  bias or -1

    hipLaunchKernelGGL(conv_k,  dim3(PLANE / 8 / 256), dim3(256), 0, stream, k, kf);
    hipLaunchKernelGGL(conv_v,  dim3(BH * 16),         dim3(256), 0, stream, v, vtf);
    hipLaunchKernelGGL(conv_bm, dim3(BMN / 4 / 256),   dim3(256), 0, stream, bias, mask, bm);
    hipLaunchKernelGGL(attn_main, dim3(BH * (L / QT)), dim3(256), 0, stream,
                       q, kf, vtf, bm, out);
}

// Round 4
// 368.182 us; speedup vs baseline: 1.8457x; 1.0330x over previous
//
#include <hip/hip_runtime.h>
#include <math.h>

typedef _Float16 f16x8 __attribute__((ext_vector_type(8)));
typedef _Float16 f16x4 __attribute__((ext_vector_type(4)));
typedef float f32x4 __attribute__((ext_vector_type(4)));

#define MFMA16(a, b, c) __builtin_amdgcn_mfma_f32_16x16x32_f16(a, b, c, 0, 0, 0)

constexpr int L = 1024;
constexpr int D = 64;
constexpr int QT = 16;                        // q rows per workgroup
constexpr int BH = 128;                       // B*H
constexpr size_t OUT_ELEMS = 8ull * 16 * 1024 * 64;
constexpr size_t PLANE = (size_t)BH * L * D;  // 8,388,608 elems
constexpr size_t BMN   = 8ull * 1024 * 1024;  // B*L*L elems

// fp16-element LDS swizzle: XOR col bits [3:5] (16B blocks) with row&7
__device__ __forceinline__ int swzh(int row, int col) {
    return row * L + (col ^ ((row & 7) << 3));
}

// ---------------- prep 1: K -> fp16 plane, 0.125 scale folded in ----------------
__global__ __launch_bounds__(256)
void conv_k(const float* __restrict__ kg, _Float16* __restrict__ kf) {
    const size_t t = ((size_t)blockIdx.x * 256 + threadIdx.x) * 8;
    float4 a0 = *(const float4*)(kg + t);
    float4 a1 = *(const float4*)(kg + t + 4);
    f16x8 o;
    o[0] = (_Float16)(0.125f * a0.x); o[1] = (_Float16)(0.125f * a0.y);
    o[2] = (_Float16)(0.125f * a0.z); o[3] = (_Float16)(0.125f * a0.w);
    o[4] = (_Float16)(0.125f * a1.x); o[5] = (_Float16)(0.125f * a1.y);
    o[6] = (_Float16)(0.125f * a1.z); o[7] = (_Float16)(0.125f * a1.w);
    *(f16x8*)(kf + t) = o;
}

// ------- prep 2: V [bh][k][d] -> fp16 Vt [bh][d][k] (transpose via LDS) -------
__global__ __launch_bounds__(256)
void conv_v(const float* __restrict__ vg, _Float16* __restrict__ vtf) {
    __shared__ _Float16 tile[64][72];
    const int bh = blockIdx.x >> 4;
    const int k0 = (blockIdx.x & 15) * 64;
    const int tid = threadIdx.x;
#pragma unroll
    for (int r = 0; r < 4; ++r) {
        const int k  = r * 16 + (tid >> 4);
        const int d0 = (tid & 15) * 4;
        float4 a = *(const float4*)(vg + ((size_t)(bh * L + k0 + k)) * D + d0);
        tile[d0 + 0][k] = (_Float16)a.x;
        tile[d0 + 1][k] = (_Float16)a.y;
        tile[d0 + 2][k] = (_Float16)a.z;
        tile[d0 + 3][k] = (_Float16)a.w;
    }
    __syncthreads();
#pragma unroll
    for (int w = 0; w < 4; ++w) {
        const int d   = w * 16 + (tid >> 4);
        const int kk0 = (tid & 15) * 4;
        const size_t dst = (size_t)bh * (D * L) + (size_t)d * L + k0 + kk0;
        *(f16x4*)(vtf + dst) = *(const f16x4*)&tile[d][kk0];
    }
}

// ---- prep 3: bias+mask -> permuted fp16 bm plane matching MFMA D-layout ----
// Region per (b,qt,wave): 4096 fp16. Within region:
//   value at byte-chunk addr (g*64 + lam)*8 + s'  (g in [0,8), lam in [0,64), s' in [0,8))
//   corresponds to slot = 8g + s' = ct*4 + r, and equals
//   (mask ? bias : -1) at [b][qt*16 + (lam&15)][wave*256 + ct*16 + 4*(lam>>4) + r]
__global__ __launch_bounds__(256)
void conv_bm(const float* __restrict__ bias, const int* __restrict__ mask,
             _Float16* __restrict__ bmp) {
    __shared__ float tile[16][260];
    const int wgid = blockIdx.x;              // (b*64+qt)*4 + wave
    const int wave = wgid & 3;
    const int bqt  = wgid >> 2;
    const int qt = bqt & 63;
    const int b  = bqt >> 6;
    const int tid = threadIdx.x;
    const size_t rowbase = ((size_t)b * L + qt * 16) * L + wave * 256;
#pragma unroll 4
    for (int rr = 0; rr < 16; ++rr) {
        float bv = bias[rowbase + (size_t)rr * L + tid];
        int   mv = mask[rowbase + (size_t)rr * L + tid];
        tile[rr][tid] = mv ? bv : -1.0f;
    }
    __syncthreads();
    _Float16* out = bmp + (size_t)wgid * 4096;
#pragma unroll
    for (int h = 0; h < 2; ++h) {
        const int vidx = h * 256 + tid;
        const int lam = vidx & 63;
        const int lr = lam & 15, lg = lam >> 4;
        const int g = vidx >> 6;
        f16x8 o;
#pragma unroll
        for (int s = 0; s < 8; ++s) {
            const int slot = g * 8 + s;
            const int ct = slot >> 2, r = slot & 3;
            o[s] = (_Float16)tile[lr][ct * 16 + 4 * lg + r];
        }
        *(f16x8*)(out + (size_t)vidx * 8) = o;
    }
}

// ---------------- main fused kernel ----------------
__global__ __launch_bounds__(256, 4)
void attn_main(const float* __restrict__ qg, const _Float16* __restrict__ kf_g,
               const _Float16* __restrict__ vtf_g, const _Float16* __restrict__ bmp_g,
               float* __restrict__ outg) {
    __shared__ __align__(16) _Float16 plds[QT * L];   // 32 KiB: P fp16
    __shared__ float red[4][16][2];                   // {local max, local sum}

    // bijective XCD swizzle: 8192 % 8 == 0
    const int wg = (blockIdx.x & 7) * 1024 + (blockIdx.x >> 3);
    const int bh = wg >> 6;
    const int qt = wg & 63;
    const int b  = bh >> 4;
    const int q0 = qt * QT;
    const int tid  = threadIdx.x;
    const int wave = tid >> 6;
    const int lane = tid & 63;
    const int lg   = lane >> 4;
    const int lr   = lane & 15;

    const float*    qp = qg + (size_t)bh * L * D;
    const _Float16* kp = kf_g + (size_t)bh * L * D;

    // Q as B-frag: col(q) = lr -> row q0+lr, k(d) = lg*8 + j
    f16x8 qf[2];
#pragma unroll
    for (int s = 0; s < 2; ++s) {
        const float* src = qp + (size_t)(q0 + lr) * D + s * 32 + lg * 8;
        float4 a0 = *(const float4*)src;
        float4 a1 = *(const float4*)(src + 4);
        f16x8 t;
        t[0] = (_Float16)a0.x; t[1] = (_Float16)a0.y;
        t[2] = (_Float16)a0.z; t[3] = (_Float16)a0.w;
        t[4] = (_Float16)a1.x; t[5] = (_Float16)a1.y;
        t[6] = (_Float16)a1.z; t[7] = (_Float16)a1.w;
        qf[s] = t;
    }

    // ---- swapped QK^T: acc[ct] holds S for q = q0+lr, keys cbase+16ct+4lg+r ----
    const int cbase = wave * 256;
    f32x4 acc[16];
#pragma unroll
    for (int ct = 0; ct < 16; ++ct) {
        const _Float16* krow = kp + (size_t)(cbase + ct * 16 + lr) * D + lg * 8;
        f16x8 kv0 = *(const f16x8*)(krow);
        f16x8 kv1 = *(const f16x8*)(krow + 32);
        f32x4 a = {0.f, 0.f, 0.f, 0.f};
        a = MFMA16(kv0, qf[0], a);
        a = MFMA16(kv1, qf[1], a);
        acc[ct] = a;
    }

    // ---- bias*mask apply (coalesced permuted fp16 plane) ----
    const _Float16* bmr = bmp_g + ((size_t)(b * 64 + qt) * 4 + wave) * 4096;
#pragma unroll
    for (int g = 0; g < 8; ++g) {
        f16x8 bv = *(const f16x8*)(bmr + g * 512 + lane * 8);
#pragma unroll
        for (int s = 0; s < 8; ++s) {
            float t = (float)bv[s];
            float a = acc[2 * g + (s >> 2)][s & 3];
            acc[2 * g + (s >> 2)][s & 3] = (t >= 0.f) ? a * t : -INFINITY;
        }
    }

    // ---- in-register softmax over this wave's 256-key chunk ----
    float m = -INFINITY;
#pragma unroll
    for (int ct = 0; ct < 16; ++ct)
#pragma unroll
        for (int r = 0; r < 4; ++r) m = fmaxf(m, acc[ct][r]);
    m = fmaxf(m, __shfl_xor(m, 16));
    m = fmaxf(m, __shfl_xor(m, 32));
    m = fmaxf(m, -10000.0f);                  // guard all-masked chunk

    float lsum = 0.f;
#pragma unroll
    for (int ct = 0; ct < 16; ++ct)
#pragma unroll
        for (int r = 0; r < 4; ++r) {
            float p = __expf(acc[ct][r] - m);  // exp(-inf)=0 for masked
            acc[ct][r] = p;
            lsum += p;
        }
    lsum += __shfl_xor(lsum, 16);
    lsum += __shfl_xor(lsum, 32);

    if (lg == 0) { red[wave][lr][0] = m; red[wave][lr][1] = lsum; }
    __syncthreads();

    float M = -INFINITY;
#pragma unroll
    for (int w = 0; w < 4; ++w) M = fmaxf(M, red[w][lr][0]);
    float denom = 0.f;
#pragma unroll
    for (int w = 0; w < 4; ++w) denom += red[w][lr][1] * __expf(red[w][lr][0] - M);
    denom = fmaxf(denom, 1e-37f);
    const float scale = __expf(m - M) / denom;

    // ---- P -> LDS fp16 (normalized) ----
#pragma unroll
    for (int ct = 0; ct < 16; ++ct) {
        f16x4 pv;
#pragma unroll
        for (int r = 0; r < 4; ++r) pv[r] = (_Float16)(acc[ct][r] * scale);
        *(f16x4*)&plds[swzh(lr, cbase + ct * 16 + 4 * lg)] = pv;
    }
    __syncthreads();

    // ---- score write: wave w owns rows 4w..4w+3, fully coalesced 1KB/instr ----
    float* srow0 = outg + OUT_ELEMS + (size_t)bh * L * L + (size_t)(q0 + wave * 4) * L;
#pragma unroll
    for (int rr = 0; rr < 4; ++rr) {
#pragma unroll
        for (int mt = 0; mt < 4; ++mt) {
            const int col = mt * 256 + lane * 4;
            f16x4 pv = *(const f16x4*)&plds[swzh(wave * 4 + rr, col)];
            float4 o = {(float)pv[0], (float)pv[1], (float)pv[2], (float)pv[3]};
            *(float4*)(srow0 + (size_t)rr * L + col) = o;
        }
    }

    // ---- PV: wave w owns d columns [16w,16w+16) ----
    const int d0 = wave * 16;
    const _Float16* vrow = vtf_g + (size_t)bh * D * L + (size_t)(d0 + lr) * L;
    f32x4 oacc = {0.f, 0.f, 0.f, 0.f};
#pragma unroll 4
    for (int kb = 0; kb < L; kb += 32) {
        const int e0 = kb + lg * 8;
        f16x8 pa = *(const f16x8*)&plds[swzh(lr, e0)];
        f16x8 vb = *(const f16x8*)(vrow + e0);
        oacc = MFMA16(pa, vb, oacc);
    }
#pragma unroll
    for (int r = 0; r < 4; ++r) {
        outg[((size_t)bh * L + q0 + lg * 4 + r) * D + d0 + lr] = oacc[r];
    }
}

extern "C" void kernel_launch(void* const* d_in, const int* in_sizes, int n_in,
                              void* d_out, int out_size, void* d_ws, size_t ws_size,
                              hipStream_t stream) {
    const float* q    = (const float*)d_in[0];
    const float* k    = (const float*)d_in[1];
    const float* v    = (const float*)d_in[2];
    const float* bias = (const float*)d_in[3];
    const int*   mask = (const int*)d_in[4];
    float* out = (float*)d_out;

    const size_t need = (2 * PLANE + BMN) * sizeof(_Float16);   // ~50 MiB
    if (ws_size < need) return;               // empirically ws_size >= 64 MiB

    _Float16* kf  = (_Float16*)d_ws;          // [BH][L][D] fp16, pre-scaled 0.125
    _Float16* vtf = kf + PLANE;               // [BH][D][L] fp16
    _Float16* bmp = vtf + PLANE;              // permuted fp16 bias/mask plane

    hipLaunchKernelGGL(conv_k,  dim3(PLANE / 8 / 256), dim3(256), 0, stream, k, kf);
    hipLaunchKernelGGL(conv_v,  dim3(BH * 16),         dim3(256), 0, stream, v, vtf);
    hipLaunchKernelGGL(conv_bm, dim3(8 * 64 * 4),      dim3(256), 0, stream, bias, mask, bmp);
    hipLaunchKernelGGL(attn_main, dim3(BH * (L / QT)), dim3(256), 0, stream,
                       q, kf, vtf, bmp, out);
}